// Round 8
// baseline (122.556 us; speedup 1.0000x reference)
//
#include <hip/hip_runtime.h>

// pos/seq_lens fill for ragged batch metadata.
// d_out layout (int32): [0, num_tokens) = pos, [num_tokens, +max_num_reqs) = seq_lens.
//
// R8: uniform tiles + block-uniform scalar segment loop.
// Evidence trail: NT stores removed the ~40us L2 write-allocate floor (R5);
// per-LANE searches cost 44us (R6); per-request blocks (zero search) tie R5
// at ~16-20us due to imbalance/straggler (R7). So: fixed 8192-token tiles
// (2048 blocks, 32KB each -- perfectly balanced), ONE scalar binary search
// per block (13 dependent s_loads, block-uniform, overlapped across 8
// co-resident blocks/CU), then a wave-uniform loop over the requests
// intersecting the tile: 3 s_loads per segment, lanes stream base+t with
// aligned NT int4 stores. Zero per-lane dependent load chains.

#define TPB 256
#define TILE_TOK 8192                       // tokens per pos block
#define SEQ_PER_BLOCK (TPB * 4)             // 1024

typedef int vint4 __attribute__((ext_vector_type(4)));

__global__ __launch_bounds__(TPB) void fused_kernel(
    const int* __restrict__ idx_mapping,
    const int* __restrict__ qsl,          // [num_reqs+1]
    const int* __restrict__ nct,          // [max_num_reqs]
    int* __restrict__ pos_out,            // [num_tokens]
    int* __restrict__ seq_out,            // [max_num_reqs]
    int num_reqs, int max_num_reqs, int num_tokens,
    int pos_blocks)
{
    int b = blockIdx.x;
    int tid = (int)threadIdx.x;

    if (b >= pos_blocks) {
        // ---- seq_lens (incl. zero tail past num_reqs; d_out is poisoned) ----
        int i = (b - pos_blocks) * SEQ_PER_BLOCK + tid * 4;
        if (i >= max_num_reqs) return;
        vint4 v;
        #pragma unroll
        for (int k = 0; k < 4; ++k) {
            int idx = i + k;
            int val = 0;
            if (idx < num_reqs)
                val = nct[idx_mapping[idx]] + (qsl[idx + 1] - qsl[idx]);
            v[k] = val;
        }
        if (i + 4 <= max_num_reqs) {
            *(vint4*)(seq_out + i) = v;
        } else {
            for (int k = 0; k < max_num_reqs - i; ++k) seq_out[i + k] = v[k];
        }
        return;
    }

    // ---- pos: one 8192-token tile, block-uniform control ----
    long long lo_l = (long long)b * TILE_TOK;
    if (lo_l >= num_tokens) return;
    int lo = (int)lo_l;
    int hi = (int)(lo_l + TILE_TOK > (long long)num_tokens ? num_tokens
                                                          : lo_l + TILE_TOK);

    // scalar binary search: last r in [0, num_reqs] with qsl[r] <= lo.
    // lo is blockIdx-derived (wave-uniform) -> compiles to s_load chain.
    int l = 0, h = num_reqs + 1;
    while (h - l > 1) {
        int mid = (l + h) >> 1;
        if (qsl[mid] <= lo) l = mid; else h = mid;
    }
    int r = l;

    int seg_lo = lo;
    while (seg_lo < hi) {
        int q1 = qsl[r + 1];                  // uniform -> s_load
        int seg_hi = (q1 < hi) ? q1 : hi;
        if (seg_hi > seg_lo) {
            int base = nct[idx_mapping[r]] - qsl[r];   // uniform s_load chain
            // head: scalar stores until 16B alignment
            int a = (seg_lo + 3) & ~3;
            if (a > seg_hi) a = seg_hi;
            if (tid < a - seg_lo) pos_out[seg_lo + tid] = base + seg_lo + tid;
            // body: aligned NT int4 stores
            int e4 = a + ((seg_hi - a) & ~3);
            for (int t = a + tid * 4; t < e4; t += TPB * 4) {
                vint4 v;
                v[0] = base + t;     v[1] = base + t + 1;
                v[2] = base + t + 2; v[3] = base + t + 3;
                __builtin_nontemporal_store(v, (vint4*)(pos_out + t));
            }
            // tail: up to 3 scalar stores
            if (tid < seg_hi - e4) pos_out[e4 + tid] = base + e4 + tid;
        }
        seg_lo = seg_hi;
        ++r;                                   // also skips empty requests
    }
}

extern "C" void kernel_launch(void* const* d_in, const int* in_sizes, int n_in,
                              void* d_out, int out_size, void* d_ws, size_t ws_size,
                              hipStream_t stream) {
    const int* idx_mapping = (const int*)d_in[0];
    const int* qsl         = (const int*)d_in[1];
    const int* nct         = (const int*)d_in[2];
    // d_in[3] (pos buffer) and d_in[4] (seq_lens buffer) are unused inputs.

    int num_reqs     = in_sizes[0];
    int max_num_reqs = in_sizes[2];
    int num_tokens   = in_sizes[3];

    int* out = (int*)d_out;
    int* pos_out = out;
    int* seq_out = out + num_tokens;

    int pos_blocks = (int)(((long long)num_tokens + TILE_TOK - 1) / TILE_TOK);  // 2048
    int seq_blocks = (max_num_reqs + SEQ_PER_BLOCK - 1) / SEQ_PER_BLOCK;        // 16

    fused_kernel<<<dim3(pos_blocks + seq_blocks), dim3(TPB), 0, stream>>>(
        idx_mapping, qsl, nct, pos_out, seq_out,
        num_reqs, max_num_reqs, num_tokens, pos_blocks);
}

// Round 9
// 119.549 us; speedup vs baseline: 1.0252x; 1.0252x over previous
//
#include <hip/hip_runtime.h>

// pos/seq_lens fill for ragged batch metadata.
// d_out layout (int32): [0, num_tokens) = pos, [num_tokens, +max_num_reqs) = seq_lens.
//
// R9 = champion R5 resubmitted. Evidence trail across the session:
//  - R2/R3: regular int4 stores hit an L2 write-allocate pathology: 64MB pos
//    stream at 1.5 TB/s (~40us) regardless of search structure.
//  - R5: nontemporal stores -> ~15us pos + ~3.5us prep (best total 119.4).
//  - R6: per-lane 13-step binary search costs 44us even with NT stores
//    (dependent-load latency, not hidden at 32 waves/CU).
//  - R7 (per-request blocks) and R8 (uniform tiles + scalar segment loop):
//    119-123, tie with R5 within harness noise.
// Floor arithmetic: ~100-104us fixed harness restore/poison + 64MB NT write
// at measured ~4.3 TB/s drain + launch overhead. WRITE_SIZE is exactly
// ideal; FETCH < 1MB; no conflicts. Remaining headroom <= ~4% of total.
//
//  - prep kernel: (a) base_req[r] = nct[idx_mapping[r]] - qsl[r],
//    (b) tile_req[j] = owning request of token j*1024, (c) seq_lens
//    (incl. zero tail past num_reqs -- d_out is poisoned 0xAA).
//  - hot kernel (16384 blocks x 256 thr, 1 int4/thread): tile inside one
//    request (~60%) -> pure stream pos = t + scalar_base; else short
//    linear advance via qsl/base_req. Nontemporal 16B stores.

#define TPB 256
#define TILE_TOK 1024                       // tokens per hot block (1 int4/thread)
#define SEQ_PER_BLOCK (TPB * 4)             // 1024

typedef int vint4 __attribute__((ext_vector_type(4)));

// ---------- prep: base_req + tile_req + seq_lens ----------
__global__ __launch_bounds__(TPB) void prep_kernel(
    const int* __restrict__ idx_mapping,
    const int* __restrict__ qsl,          // [num_reqs+1]
    const int* __restrict__ nct,          // [max_num_reqs]
    int* __restrict__ tile_req,           // [num_tiles+1]   (d_ws)
    int* __restrict__ base_req,           // [num_reqs]      (d_ws)
    int* __restrict__ seq_out,            // [max_num_reqs]
    int num_reqs, int max_num_reqs, int num_tokens,
    int bound_count, int bound_blocks)
{
    int b = blockIdx.x;
    if (b < bound_blocks) {
        int j = b * TPB + (int)threadIdx.x;
        if (j >= bound_count) return;
        long long tl = (long long)j * TILE_TOK;
        int t = (tl >= num_tokens) ? (num_tokens - 1) : (int)tl;
        // last r in [0, num_reqs] with qsl[r] <= t  (== searchsorted-right - 1)
        int l = 0, h = num_reqs + 1;
        while (h - l > 1) {
            int mid = (l + h) >> 1;
            if (qsl[mid] <= t) l = mid; else h = mid;
        }
        tile_req[j] = l;
        return;
    }
    // ---- base_req + seq_lens ----
    int i = (b - bound_blocks) * SEQ_PER_BLOCK + (int)threadIdx.x * 4;
    if (i >= max_num_reqs) return;
    vint4 v;
    #pragma unroll
    for (int k = 0; k < 4; ++k) {
        int idx = i + k;
        int val = 0;
        if (idx < num_reqs) {
            int q0 = qsl[idx], q1 = qsl[idx + 1];
            int nb = nct[idx_mapping[idx]];
            base_req[idx] = nb - q0;
            val = nb + (q1 - q0);
        }
        v[k] = val;
    }
    if (i + 4 <= max_num_reqs) {
        *(vint4*)(seq_out + i) = v;
    } else {
        for (int k = 0; k < max_num_reqs - i; ++k) seq_out[i + k] = v[k];
    }
}

// ---------- hot: pos fill ----------
__global__ __launch_bounds__(TPB) void pos_kernel(
    const int* __restrict__ qsl,          // [num_reqs+1]
    const int* __restrict__ tile_req,     // [num_tiles+1]
    const int* __restrict__ base_req,     // [num_reqs]
    int* __restrict__ pos_out,            // [num_tokens]
    int num_tokens)
{
    int tile = blockIdx.x;
    int t = tile * TILE_TOK + (int)threadIdx.x * 4;
    if (t >= num_tokens) return;

    int r0 = tile_req[tile];              // wave-uniform (s_load)
    int r1 = tile_req[tile + 1];
    vint4 v;

    if (r0 == r1) {
        // whole tile inside one request: pure stream
        int base = base_req[r0];          // wave-uniform
        v[0] = t + base; v[1] = t + 1 + base;
        v[2] = t + 2 + base; v[3] = t + 3 + base;
    } else {
        int r = r0;
        while (qsl[r + 1] <= t) ++r;      // advance to this thread's request
        int next = qsl[r + 1];
        int base = base_req[r];
        #pragma unroll
        for (int k = 0; k < 4; ++k) {
            int tk = t + k;
            while (tk >= next) {          // handles empty requests too
                ++r;
                next = qsl[r + 1];
                base = base_req[r];
            }
            v[k] = base + tk;
        }
    }

    if (t + 4 <= num_tokens) {
        __builtin_nontemporal_store(v, (vint4*)(pos_out + t));
    } else {
        for (int k = 0; k < num_tokens - t; ++k) pos_out[t + k] = v[k];
    }
}

extern "C" void kernel_launch(void* const* d_in, const int* in_sizes, int n_in,
                              void* d_out, int out_size, void* d_ws, size_t ws_size,
                              hipStream_t stream) {
    const int* idx_mapping = (const int*)d_in[0];
    const int* qsl         = (const int*)d_in[1];
    const int* nct         = (const int*)d_in[2];
    // d_in[3] (pos buffer) and d_in[4] (seq_lens buffer) are unused inputs.

    int num_reqs     = in_sizes[0];
    int max_num_reqs = in_sizes[2];
    int num_tokens   = in_sizes[3];

    int* out = (int*)d_out;
    int* pos_out = out;
    int* seq_out = out + num_tokens;

    int num_tiles   = (int)(((long long)num_tokens + TILE_TOK - 1) / TILE_TOK); // 16384
    int bound_count = num_tiles + 1;                                            // 16385
    int* tile_req = (int*)d_ws;
    int* base_req = tile_req + (bound_count + 3) / 4 * 4;

    int bound_blocks = (bound_count + TPB - 1) / TPB;                           // 65
    int seq_blocks   = (max_num_reqs + SEQ_PER_BLOCK - 1) / SEQ_PER_BLOCK;      // 16

    prep_kernel<<<dim3(bound_blocks + seq_blocks), dim3(TPB), 0, stream>>>(
        idx_mapping, qsl, nct, tile_req, base_req, seq_out,
        num_reqs, max_num_reqs, num_tokens, bound_count, bound_blocks);

    pos_kernel<<<dim3(num_tiles), dim3(TPB), 0, stream>>>(
        qsl, tile_req, base_req, pos_out, num_tokens);
}